// Round 1
// baseline (4266.213 us; speedup 1.0000x reference)
//
#include <hip/hip_runtime.h>

// ---------------------------------------------------------------------------
// QMon (monDEQ) full pipeline, fp32.
//  conv1(8x8,s4)+relu -> conv2(4x4,s2)+relu -> monDEQ PR solver (freq domain)
//  -> border crop -> fc1+relu -> fc2
// Solver: z12 = V(w)^-1 applied per 2D-DFT frequency (9x9), V = (1+a)I - aW,
//         W = (1-m)I - g A^H A  with A Frobenius-normalized.
// ---------------------------------------------------------------------------

#define NB 256      // batch
#define NCH 64      // DEQ channels
#define NP 81       // 9x9 pixels / freqs
#define NIMG (NB*NCH)
#define TOLF 1e-5f
#define MAXIT 50

__constant__ float COS9[9] = {
  1.0f, 0.76604444311897803f, 0.17364817766693041f, -0.5f,
  -0.93969262078590843f, -0.93969262078590843f, -0.5f,
  0.17364817766693041f, 0.76604444311897803f };
__constant__ float SIN9[9] = {
  0.0f, 0.64278760968653936f, 0.98480775301220802f, 0.86602540378443871f,
  0.34202014332566877f, -0.34202014332566877f, -0.86602540378443871f,
  -0.98480775301220802f, -0.64278760968653936f };

// ---------------- norm of A_w -------------------------------------------
__global__ __launch_bounds__(256) void k_norm(const float* __restrict__ Aw,
                                              float* __restrict__ sc) {
    __shared__ float red[256];
    float s = 0.f;
    for (int i = threadIdx.x; i < 64*64*9; i += 256) { float a = Aw[i]; s += a*a; }
    red[threadIdx.x] = s; __syncthreads();
    for (int w = 128; w > 0; w >>= 1) {
        if (threadIdx.x < w) red[threadIdx.x] += red[threadIdx.x + w];
        __syncthreads();
    }
    if (threadIdx.x == 0) { float n = sqrtf(red[0]); sc[0] = n; sc[1] = 1.f/n; }
}

// ---------------- conv1: (256,4,84,84)->(256,32,20,20), k8 s4, relu, x/255 --
__global__ __launch_bounds__(256) void k_conv1(const float* __restrict__ x,
                                               const float* __restrict__ w,
                                               const float* __restrict__ bb,
                                               float* __restrict__ y) {
    int blk = blockIdx.x;
    int b = blk >> 2, og = (blk & 3) << 3;        // 8 out-channels per block
    __shared__ float wl[2048];                    // 8 oc * 256 taps
    for (int i = threadIdx.x; i < 2048; i += 256) wl[i] = w[og*256 + i];
    __syncthreads();
    const float* xb = x + b*28224;
    for (int p = threadIdx.x; p < 400; p += 256) {
        int oy = p/20, ox = p%20;
        float acc[8];
        #pragma unroll
        for (int o = 0; o < 8; o++) acc[o] = 0.f;
        for (int ci = 0; ci < 4; ci++)
        for (int ky = 0; ky < 8; ky++) {
            const float* xr = xb + ci*7056 + (oy*4+ky)*84 + ox*4;
            const float* wr = wl + ci*64 + ky*8;
            #pragma unroll
            for (int kx = 0; kx < 8; kx++) {
                float v = xr[kx];
                #pragma unroll
                for (int o = 0; o < 8; o++) acc[o] += v * wr[o*256 + kx];
            }
        }
        #pragma unroll
        for (int o = 0; o < 8; o++)
            y[b*12800 + (og+o)*400 + p] = fmaxf(acc[o]*(1.f/255.f) + bb[og+o], 0.f);
    }
}

// ---------------- conv2: (256,32,20,20)->(256,64,9,9), k4 s2, relu ---------
__global__ __launch_bounds__(256) void k_conv2(const float* __restrict__ h1,
                                               const float* __restrict__ w,
                                               const float* __restrict__ bb,
                                               float* __restrict__ h2) {
    int b = blockIdx.x;
    __shared__ float hl[12800];
    for (int i = threadIdx.x; i < 12800; i += 256) hl[i] = h1[b*12800 + i];
    __syncthreads();
    for (int idx = threadIdx.x; idx < 5184; idx += 256) {
        int o = idx/81, p = idx%81, oy = p/9, ox = p%9;
        float acc = 0.f;
        const float* wo = w + o*512;
        for (int ci = 0; ci < 32; ci++) {
            const float* hb = hl + ci*400 + oy*40 + ox*2;
            const float* wb = wo + ci*16;
            #pragma unroll
            for (int ky = 0; ky < 4; ky++)
            #pragma unroll
            for (int kx = 0; kx < 4; kx++)
                acc += hb[ky*20 + kx] * wb[ky*4 + kx];
        }
        h2[b*5184 + idx] = fmaxf(acc + bb[o], 0.f);
    }
}

// ---------------- bias = circ_conv3x3(h2, U_w) + U_b -----------------------
__global__ __launch_bounds__(256) void k_bias(const float* __restrict__ h2,
                                              const float* __restrict__ Uw,
                                              const float* __restrict__ Ub,
                                              float* __restrict__ bias) {
    int b = blockIdx.x;
    __shared__ float hl[5184];
    for (int i = threadIdx.x; i < 5184; i += 256) hl[i] = h2[b*5184 + i];
    __syncthreads();
    for (int idx = threadIdx.x; idx < 5184; idx += 256) {
        int o = idx/81, p = idx%81, i0 = p/9, j0 = p%9;
        int im = (i0+8)%9, ip = (i0+1)%9, jm = (j0+8)%9, jp = (j0+1)%9;
        int r0 = im*9, r1 = i0*9, r2 = ip*9;
        float acc = 0.f;
        const float* wo = Uw + o*576;
        for (int ci = 0; ci < 64; ci++) {
            const float* hb = hl + ci*81;
            const float* wb = wo + ci*9;
            acc += hb[r0+jm]*wb[0] + hb[r0+j0]*wb[1] + hb[r0+jp]*wb[2]
                 + hb[r1+jm]*wb[3] + hb[r1+j0]*wb[4] + hb[r1+jp]*wb[5]
                 + hb[r2+jm]*wb[6] + hb[r2+j0]*wb[7] + hb[r2+jp]*wb[8];
        }
        bias[b*5184 + idx] = acc + Ub[o];
    }
}

// ---------------- Af(w)[o][i] = sum An[o,i,dx,dy] e^{+2pi i(x(dx-1)+y(dy-1))/9}
__global__ __launch_bounds__(256) void k_af(const float* __restrict__ Aw,
                                            const float* __restrict__ sc,
                                            float2* __restrict__ Af) {
    int f = blockIdx.x; int x = f/9, y = f%9;
    float inv = sc[1];
    for (int pr = threadIdx.x; pr < 4096; pr += 256) {
        const float* a = Aw + pr*9;
        float re = 0.f, im = 0.f;
        #pragma unroll
        for (int dx = 0; dx < 3; dx++)
        #pragma unroll
        for (int dy = 0; dy < 3; dy++) {
            int tt = (x*(dx+8) + y*(dy+8)) % 9;   // (dx-1) mod 9
            float v = a[dx*3+dy] * inv;
            re += v * COS9[tt]; im += v * SIN9[tt];
        }
        Af[f*4096 + pr] = make_float2(re, im);
    }
}

// ---------------- M = 1.1 I + g A^H A ; W^T = (0.9 I - g A^H A)^T ----------
__global__ __launch_bounds__(256) void k_mw(const float2* __restrict__ Af,
                                            const float* __restrict__ gp,
                                            float2* __restrict__ Mmat,
                                            float2* __restrict__ WmT) {
    int f = blockIdx.x;
    float g = gp[0];
    __shared__ float2 Al[4096];
    for (int i = threadIdx.x; i < 4096; i += 256) Al[i] = Af[f*4096 + i];
    __syncthreads();
    for (int e = threadIdx.x; e < 4096; e += 256) {
        int i = e >> 6, j = e & 63;
        float sr = 0.f, si = 0.f;
        for (int o = 0; o < 64; o++) {
            float2 a = Al[o*64 + i], b = Al[o*64 + j];
            sr += a.x*b.x + a.y*b.y;      // conj(a)*b
            si += a.x*b.y - a.y*b.x;
        }
        Mmat[f*4096 + e] = make_float2((i==j ? 1.1f : 0.f) + g*sr, g*si);
        WmT [f*4096 + j*64 + i] = make_float2((i==j ? 0.9f : 0.f) - g*sr, -g*si);
    }
}

// ---------------- in-place Gauss-Jordan inverse (no pivoting, HPD) ---------
// Reads Mmat[f][i][j], writes back transposed: Mio[f][c][o] = Minv[o][c]
__global__ __launch_bounds__(256) void k_inv(float2* __restrict__ Mio) {
    int f = blockIdx.x;
    __shared__ float2 M[4096];
    __shared__ float2 rowk[64];
    for (int e = threadIdx.x; e < 4096; e += 256) M[e] = Mio[f*4096 + e];
    __syncthreads();
    int i = threadIdx.x >> 2, q = threadIdx.x & 3;
    for (int k = 0; k < 64; k++) {
        float2 d = M[k*64 + k];
        float den = 1.f / (d.x*d.x + d.y*d.y);
        float pr = d.x*den, pi = -d.y*den;
        if (i == k) {
            for (int j = q; j < 64; j += 4) {
                if (j == k) rowk[k] = make_float2(pr, pi);
                else { float2 m = M[k*64 + j];
                       rowk[j] = make_float2(m.x*pr - m.y*pi, m.x*pi + m.y*pr); }
            }
        }
        float2 fi = M[i*64 + k];
        __syncthreads();
        if (i == k) {
            for (int j = q; j < 64; j += 4) M[k*64 + j] = rowk[j];
        } else {
            for (int j = q; j < 64; j += 4) {
                if (j == k) M[i*64 + k] = make_float2(-(fi.x*pr - fi.y*pi),
                                                      -(fi.x*pi + fi.y*pr));
                else { float2 r = rowk[j]; float2 m = M[i*64 + j];
                       M[i*64 + j] = make_float2(m.x - (fi.x*r.x - fi.y*r.y),
                                                 m.y - (fi.x*r.y + fi.y*r.x)); }
            }
        }
        __syncthreads();
    }
    for (int e = threadIdx.x; e < 4096; e += 256) {
        int i2 = e >> 6, j2 = e & 63;
        Mio[f*4096 + j2*64 + i2] = M[e];
    }
}

// ---------------- forward: u12 = 2z-u ; FFT2(u12+bias) -> Tf[freq][img] ----
// mode 1 (final): FFT2(z).  Also: convergence check from prev iter partials.
__global__ __launch_bounds__(256) void k_ffwd(const float* __restrict__ z,
                                              const float* __restrict__ u,
                                              const float* __restrict__ bias,
                                              float* __restrict__ u12,
                                              float2* __restrict__ Tf,
                                              const float2* __restrict__ errp,
                                              int* __restrict__ flag,
                                              int iter, int mode) {
    __shared__ float  tre[16][81];
    __shared__ float2 S[16][81];
    __shared__ float2 red2[256];
    int tid = threadIdx.x;
    if (mode == 0 && iter > 0) {
        // every block deterministically recomputes err of iter-1 (fixed order)
        float d2 = 0.f, n2 = 0.f;
        const float2* ep = errp + (iter-1)*1024;
        for (int qq = tid; qq < 1024; qq += 256) { float2 e = ep[qq]; d2 += e.x; n2 += e.y; }
        red2[tid] = make_float2(d2, n2);
        __syncthreads();
        for (int w = 128; w > 0; w >>= 1) {
            if (tid < w) { red2[tid].x += red2[tid+w].x; red2[tid].y += red2[tid+w].y; }
            __syncthreads();
        }
        float2 t = red2[0];
        bool conv = sqrtf(t.x) <= TOLF * (1e-6f + sqrtf(t.y));
        if (conv) { if (tid == 0) *flag = 1; return; }
        __syncthreads();
    }
    int img0 = blockIdx.x * 16;
    int tl = tid & 15, th = tid >> 4;
    // phase 1: elementwise + stage input rows to LDS (img=th, p=tl+16k)
    {
        int gb = (img0 + th)*81;
        #pragma unroll
        for (int k = 0; k < 6; k++) {
            int p = tl + 16*k;
            if (p < 81) {
                float t;
                if (mode == 0) {
                    float v = 2.f*z[gb+p] - u[gb+p];
                    u12[gb+p] = v;
                    t = v + bias[gb+p];
                } else t = z[gb+p];
                tre[th][p] = t;
            }
        }
    }
    __syncthreads();
    // stage 1: R[r][ky] = sum_x t[r][x] e^{-2pi i ky x/9}
    #pragma unroll
    for (int k = 0; k < 6; k++) {
        int idx = tl + 16*k;
        if (idx < 81) {
            int r = idx/9, ky = idx%9;
            float sr = 0.f, si = 0.f;
            int tt = 0;
            #pragma unroll
            for (int xx = 0; xx < 9; xx++) {
                float v = tre[th][r*9 + xx];
                sr += v*COS9[tt]; si -= v*SIN9[tt];
                tt += ky; if (tt >= 9) tt -= 9;
            }
            S[th][idx] = make_float2(sr, si);
        }
    }
    __syncthreads();
    // stage 2: F[kx][ky] = sum_r R[r][ky] e^{-2pi i kx r/9}; coalesced write
    #pragma unroll
    for (int k = 0; k < 6; k++) {
        int idx = th + 16*k;
        if (idx < 81) {
            int kx = idx/9, ky = idx%9;
            float fr = 0.f, fim = 0.f;
            int tt = 0;
            #pragma unroll
            for (int r = 0; r < 9; r++) {
                float2 s = S[tl][r*9 + ky];
                float c = COS9[tt], sn = SIN9[tt];
                fr  += s.x*c + s.y*sn;
                fim += s.y*c - s.x*sn;
                tt += kx; if (tt >= 9) tt -= 9;
            }
            Tf[idx*NIMG + img0 + tl] = make_float2(fr, fim);
        }
    }
}

// ---------------- per-frequency complex matvec: Y = V * T ------------------
__global__ __launch_bounds__(256) void k_matvec(const float2* __restrict__ Tf,
                                                float2* __restrict__ Yf,
                                                const float2* __restrict__ V,
                                                const int* __restrict__ flag,
                                                int useflag) {
    if (useflag && *flag) return;
    int f = blockIdx.x >> 3, bc = blockIdx.x & 7;   // 81 freqs x 8 batch-chunks
    __shared__ float2 Vl[4096];        // [c][o]
    __shared__ float2 Tl[32*65];       // padded rows
    int tid = threadIdx.x;
    const float2* Vg = V + f*4096;
    for (int e = tid; e < 4096; e += 256) Vl[e] = Vg[e];
    const float2* Tg = Tf + f*NIMG + bc*2048;
    for (int e = tid; e < 2048; e += 256) Tl[(e>>6)*65 + (e&63)] = Tg[e];
    __syncthreads();
    int r = tid >> 3, to = tid & 7;
    float2 acc[8];
    #pragma unroll
    for (int k = 0; k < 8; k++) acc[k] = make_float2(0.f, 0.f);
    const float2* trow = Tl + r*65;
    for (int c = 0; c < 64; c++) {
        float2 t = trow[c];
        #pragma unroll
        for (int k = 0; k < 8; k++) {
            float2 v = Vl[c*64 + to + 8*k];
            acc[k].x += v.x*t.x - v.y*t.y;
            acc[k].y += v.x*t.y + v.y*t.x;
        }
    }
    float2* Yg = Yf + f*NIMG + bc*2048 + r*64;
    #pragma unroll
    for (int k = 0; k < 8; k++) Yg[to + 8*k] = acc[k];
}

// ---------------- inverse FFT + update (mode 0) or final crop (mode 1) -----
__global__ __launch_bounds__(256) void k_finv(const float2* __restrict__ Yf,
                                              const float* __restrict__ u12,
                                              const float* __restrict__ bias,
                                              float* __restrict__ z,
                                              float* __restrict__ u,
                                              float2* __restrict__ errp,
                                              float* __restrict__ zc,
                                              const int* __restrict__ flag,
                                              int iter, int mode) {
    if (mode == 0 && *flag) return;
    __shared__ float2 Yc[16][81];
    __shared__ float2 T1[16][81];
    __shared__ float2 red2[256];
    int tid = threadIdx.x;
    int img0 = blockIdx.x * 16;
    int tl = tid & 15, th = tid >> 4;
    #pragma unroll
    for (int k = 0; k < 6; k++) {        // coalesced load (img=tl)
        int idx = th + 16*k;
        if (idx < 81) Yc[tl][idx] = Yf[idx*NIMG + img0 + tl];
    }
    __syncthreads();
    // stage 1: T1[r][ky] = sum_kx Y[kx][ky] e^{+2pi i r kx/9}
    #pragma unroll
    for (int k = 0; k < 6; k++) {
        int idx = tl + 16*k;
        if (idx < 81) {
            int r = idx/9, ky = idx%9;
            float sr = 0.f, si = 0.f;
            int tt = 0;
            #pragma unroll
            for (int kx = 0; kx < 9; kx++) {
                float2 a = Yc[th][kx*9 + ky];
                float c = COS9[tt], sn = SIN9[tt];
                sr += a.x*c - a.y*sn;
                si += a.x*sn + a.y*c;
                tt += r; if (tt >= 9) tt -= 9;
            }
            T1[th][idx] = make_float2(sr, si);
        }
    }
    __syncthreads();
    float d2a = 0.f, n2a = 0.f;
    int gb = (img0 + th)*81;
    #pragma unroll
    for (int k = 0; k < 6; k++) {
        int p = tl + 16*k;
        if (p < 81) {
            int r = p/9, xc = p%9;
            float yr = 0.f;
            int tt = 0;
            #pragma unroll
            for (int ky = 0; ky < 9; ky++) {
                float2 a = T1[th][r*9 + ky];
                yr += a.x*COS9[tt] - a.y*SIN9[tt];
                tt += xc; if (tt >= 9) tt -= 9;
            }
            yr *= (1.f/81.f);
            bool interior = (r >= 1 && r <= 7 && xc >= 1 && xc <= 7);
            if (mode == 0) {
                float un = 2.f*yr - u12[gb+p];
                float zn = interior ? fmaxf(un, 0.f) : 0.f;
                float zo = z[gb+p];
                float d = zn - zo;
                d2a += d*d; n2a += zn*zn;
                z[gb+p] = zn; u[gb+p] = un;
            } else if (interior) {
                float zn = fmaxf(yr + bias[gb+p], 0.f);
                int img = img0 + th;
                zc[(img >> 6)*3136 + (img & 63)*49 + (r-1)*7 + (xc-1)] = zn;
            }
        }
    }
    if (mode == 0) {
        red2[tid] = make_float2(d2a, n2a);
        __syncthreads();
        for (int w = 128; w > 0; w >>= 1) {
            if (tid < w) { red2[tid].x += red2[tid+w].x; red2[tid].y += red2[tid+w].y; }
            __syncthreads();
        }
        if (tid == 0) errp[iter*1024 + blockIdx.x] = red2[0];
    }
}

// ---------------- fc1: (256x3136)x(512x3136)^T + b, relu -------------------
__global__ __launch_bounds__(256) void k_fc1(const float* __restrict__ A,
                                             const float* __restrict__ W,
                                             const float* __restrict__ bb,
                                             float* __restrict__ H) {
    int bt = blockIdx.x >> 5, ot = blockIdx.x & 31;
    int b0 = bt*16, o0 = ot*16;
    __shared__ float At[16][65], Bt[16][65];
    int tid = threadIdx.x;
    int row = tid >> 6, col = tid & 63;
    int tb = tid >> 4, to = tid & 15;
    float acc = 0.f;
    for (int k0 = 0; k0 < 3136; k0 += 64) {
        #pragma unroll
        for (int s = 0; s < 4; s++) {
            int rr = row + s*4;
            At[rr][col] = A[(b0+rr)*3136 + k0 + col];
            Bt[rr][col] = W[(o0+rr)*3136 + k0 + col];
        }
        __syncthreads();
        #pragma unroll
        for (int kk = 0; kk < 64; kk++)
            acc += At[tb][kk] * Bt[to][kk];
        __syncthreads();
    }
    H[(b0+tb)*512 + o0+to] = fmaxf(acc + bb[o0+to], 0.f);
}

// ---------------- fc2: (256x512)x(18x512)^T + b ----------------------------
__global__ __launch_bounds__(256) void k_fc2(const float* __restrict__ H,
                                             const float* __restrict__ W,
                                             const float* __restrict__ bb,
                                             float* __restrict__ out) {
    int idx = blockIdx.x*256 + threadIdx.x;
    if (idx >= 4608) return;
    int b = idx/18, o = idx%18;
    const float* h = H + b*512;
    const float* w = W + o*512;
    float acc = 0.f;
    for (int k = 0; k < 512; k++) acc += h[k]*w[k];
    out[idx] = acc + bb[o];
}

// ---------------------------------------------------------------------------
extern "C" void kernel_launch(void* const* d_in, const int* in_sizes, int n_in,
                              void* d_out, int out_size, void* d_ws, size_t ws_size,
                              hipStream_t stream) {
    (void)in_sizes; (void)n_in; (void)out_size; (void)ws_size;
    const float* x   = (const float*)d_in[0];
    const float* c1w = (const float*)d_in[1];
    const float* c1b = (const float*)d_in[2];
    const float* c2w = (const float*)d_in[3];
    const float* c2b = (const float*)d_in[4];
    const float* Uw  = (const float*)d_in[5];
    const float* Ub  = (const float*)d_in[6];
    const float* Aw  = (const float*)d_in[7];
    const float* gp  = (const float*)d_in[8];
    const float* f1w = (const float*)d_in[9];
    const float* f1b = (const float*)d_in[10];
    const float* f2w = (const float*)d_in[11];
    const float* f2b = (const float*)d_in[12];

    float* ws = (float*)d_ws;
    // float offsets (h1 aliased by Tf: h1 dead after conv2, Tf first written later)
    float*  h1   = ws + 0;                       // 3,276,800 f
    float2* Tf   = (float2*)(ws + 0);            // 1,327,104 cplx (alias h1)
    float*  h2   = ws + 3276800;                 // 1,327,104 f
    float*  bias = ws + 4603904;                 // 1,327,104 f
    float*  z    = ws + 5931008;                 // 1,327,104 f
    float*  u    = ws + 7258112;                 // 1,327,104 f
    float*  u12  = ws + 8585216;                 // 1,327,104 f
    float2* Yf   = (float2*)(ws + 9912320);      // 1,327,104 cplx
    float2* Af   = (float2*)(ws + 12566528);     // 331,776 cplx
    float2* Minv = (float2*)(ws + 13230080);     // 331,776 cplx (M -> inv, transposed)
    float2* WmT  = (float2*)(ws + 13893632);     // 331,776 cplx
    float*  zc   = ws + 14557184;                // 802,816 f
    float*  hfc  = ws + 15360000;                // 131,072 f
    float2* errp = (float2*)(ws + 15491072);     // 50*1024 cplx pairs (d2,n2)
    float*  sc   = ws + 15593472;                // nrm, invnrm
    int*    flag = (int*)(ws + 15593474);

    // zero z,u (contiguous) and errp+scalars+flag (contiguous)
    hipMemsetAsync(z, 0, (size_t)2*1327104*sizeof(float), stream);
    hipMemsetAsync(errp, 0, (size_t)(102400 + 64)*sizeof(float), stream);

    k_norm <<<1,   256, 0, stream>>>(Aw, sc);
    k_conv1<<<1024,256, 0, stream>>>(x, c1w, c1b, h1);
    k_conv2<<<256, 256, 0, stream>>>(h1, c2w, c2b, h2);
    k_bias <<<256, 256, 0, stream>>>(h2, Uw, Ub, bias);
    k_af   <<<81,  256, 0, stream>>>(Aw, sc, Af);
    k_mw   <<<81,  256, 0, stream>>>(Af, gp, Minv, WmT);
    k_inv  <<<81,  256, 0, stream>>>(Minv);

    for (int it = 0; it < MAXIT; it++) {
        k_ffwd  <<<1024,256,0,stream>>>(z, u, bias, u12, Tf, errp, flag, it, 0);
        k_matvec<<<648, 256,0,stream>>>(Tf, Yf, Minv, flag, 1);
        k_finv  <<<1024,256,0,stream>>>(Yf, u12, bias, z, u, errp, zc, flag, it, 0);
    }
    // final pass: brelu(W z + bias), write cropped (B,3136)
    k_ffwd  <<<1024,256,0,stream>>>(z, u, bias, u12, Tf, errp, flag, 0, 1);
    k_matvec<<<648, 256,0,stream>>>(Tf, Yf, WmT, flag, 0);
    k_finv  <<<1024,256,0,stream>>>(Yf, u12, bias, z, u, errp, zc, flag, 0, 1);

    k_fc1<<<512,256,0,stream>>>(zc, f1w, f1b, hfc);
    k_fc2<<<18, 256,0,stream>>>(hfc, f2w, f2b, (float*)d_out);
}

// Round 2
// 3700.790 us; speedup vs baseline: 1.1528x; 1.1528x over previous
//
#include <hip/hip_runtime.h>

// ---------------------------------------------------------------------------
// QMon (monDEQ) full pipeline, fp32.
//  conv1(8x8,s4)+relu -> conv2(4x4,s2)+relu -> monDEQ PR solver (freq domain)
//  -> border crop -> fc1+relu -> fc2
// Round 2: conflict-free k_inv, Hermitian symmetry (41/81 freqs),
//          fused finv(t)+ffwd(t+1) kernel, err-check moved into matvec.
// ---------------------------------------------------------------------------

#define NB 256
#define NCH 64
#define NP 81
#define NIMG (NB*NCH)
#define TOLF 1e-5f
#define MAXIT 50
#define NCAN 41                       // canonical freqs: {0..4} U {9..44}
#define CANON(l) ((l) < 5 ? (l) : (l) + 4)

__constant__ float COS9[9] = {
  1.0f, 0.76604444311897803f, 0.17364817766693041f, -0.5f,
  -0.93969262078590843f, -0.93969262078590843f, -0.5f,
  0.17364817766693041f, 0.76604444311897803f };
__constant__ float SIN9[9] = {
  0.0f, 0.64278760968653936f, 0.98480775301220802f, 0.86602540378443871f,
  0.34202014332566877f, -0.34202014332566877f, -0.86602540378443871f,
  -0.98480775301220802f, -0.64278760968653936f };

// ---------------- norm of A_w ----------------------------------------------
__global__ __launch_bounds__(256) void k_norm(const float* __restrict__ Aw,
                                              float* __restrict__ sc) {
    __shared__ float red[256];
    float s = 0.f;
    for (int i = threadIdx.x; i < 64*64*9; i += 256) { float a = Aw[i]; s += a*a; }
    red[threadIdx.x] = s; __syncthreads();
    for (int w = 128; w > 0; w >>= 1) {
        if (threadIdx.x < w) red[threadIdx.x] += red[threadIdx.x + w];
        __syncthreads();
    }
    if (threadIdx.x == 0) { float n = sqrtf(red[0]); sc[0] = n; sc[1] = 1.f/n; }
}

// ---------------- conv1: (256,4,84,84)->(256,32,20,20), k8 s4, relu, x/255 --
__global__ __launch_bounds__(256) void k_conv1(const float* __restrict__ x,
                                               const float* __restrict__ w,
                                               const float* __restrict__ bb,
                                               float* __restrict__ y) {
    int blk = blockIdx.x;
    int b = blk >> 2, og = (blk & 3) << 3;
    __shared__ float wl[2048];
    for (int i = threadIdx.x; i < 2048; i += 256) wl[i] = w[og*256 + i];
    __syncthreads();
    const float* xb = x + b*28224;
    for (int p = threadIdx.x; p < 400; p += 256) {
        int oy = p/20, ox = p%20;
        float acc[8];
        #pragma unroll
        for (int o = 0; o < 8; o++) acc[o] = 0.f;
        for (int ci = 0; ci < 4; ci++)
        for (int ky = 0; ky < 8; ky++) {
            const float* xr = xb + ci*7056 + (oy*4+ky)*84 + ox*4;
            const float* wr = wl + ci*64 + ky*8;
            #pragma unroll
            for (int kx = 0; kx < 8; kx++) {
                float v = xr[kx];
                #pragma unroll
                for (int o = 0; o < 8; o++) acc[o] += v * wr[o*256 + kx];
            }
        }
        #pragma unroll
        for (int o = 0; o < 8; o++)
            y[b*12800 + (og+o)*400 + p] = fmaxf(acc[o]*(1.f/255.f) + bb[og+o], 0.f);
    }
}

// ---------------- conv2: (256,32,20,20)->(256,64,9,9), k4 s2, relu ---------
__global__ __launch_bounds__(256) void k_conv2(const float* __restrict__ h1,
                                               const float* __restrict__ w,
                                               const float* __restrict__ bb,
                                               float* __restrict__ h2) {
    int b = blockIdx.x;
    __shared__ float hl[12800];
    for (int i = threadIdx.x; i < 12800; i += 256) hl[i] = h1[b*12800 + i];
    __syncthreads();
    for (int idx = threadIdx.x; idx < 5184; idx += 256) {
        int o = idx/81, p = idx%81, oy = p/9, ox = p%9;
        float acc = 0.f;
        const float* wo = w + o*512;
        for (int ci = 0; ci < 32; ci++) {
            const float* hb = hl + ci*400 + oy*40 + ox*2;
            const float* wb = wo + ci*16;
            #pragma unroll
            for (int ky = 0; ky < 4; ky++)
            #pragma unroll
            for (int kx = 0; kx < 4; kx++)
                acc += hb[ky*20 + kx] * wb[ky*4 + kx];
        }
        h2[b*5184 + idx] = fmaxf(acc + bb[o], 0.f);
    }
}

// ---------------- bias = circ_conv3x3(h2, U_w) + U_b -----------------------
__global__ __launch_bounds__(256) void k_bias(const float* __restrict__ h2,
                                              const float* __restrict__ Uw,
                                              const float* __restrict__ Ub,
                                              float* __restrict__ bias) {
    int b = blockIdx.x;
    __shared__ float hl[5184];
    for (int i = threadIdx.x; i < 5184; i += 256) hl[i] = h2[b*5184 + i];
    __syncthreads();
    for (int idx = threadIdx.x; idx < 5184; idx += 256) {
        int o = idx/81, p = idx%81, i0 = p/9, j0 = p%9;
        int im = (i0+8)%9, ip = (i0+1)%9, jm = (j0+8)%9, jp = (j0+1)%9;
        int r0 = im*9, r1 = i0*9, r2 = ip*9;
        float acc = 0.f;
        const float* wo = Uw + o*576;
        for (int ci = 0; ci < 64; ci++) {
            const float* hb = hl + ci*81;
            const float* wb = wo + ci*9;
            acc += hb[r0+jm]*wb[0] + hb[r0+j0]*wb[1] + hb[r0+jp]*wb[2]
                 + hb[r1+jm]*wb[3] + hb[r1+j0]*wb[4] + hb[r1+jp]*wb[5]
                 + hb[r2+jm]*wb[6] + hb[r2+j0]*wb[7] + hb[r2+jp]*wb[8];
        }
        bias[b*5184 + idx] = acc + Ub[o];
    }
}

// ---------------- Af(f) for canonical f only -------------------------------
__global__ __launch_bounds__(256) void k_af(const float* __restrict__ Aw,
                                            const float* __restrict__ sc,
                                            float2* __restrict__ Af) {
    int l = blockIdx.x; int f = CANON(l);
    int x = f/9, y = f%9;
    float inv = sc[1];
    for (int pr = threadIdx.x; pr < 4096; pr += 256) {
        const float* a = Aw + pr*9;
        float re = 0.f, im = 0.f;
        #pragma unroll
        for (int dx = 0; dx < 3; dx++)
        #pragma unroll
        for (int dy = 0; dy < 3; dy++) {
            int tt = (x*(dx+8) + y*(dy+8)) % 9;
            float v = a[dx*3+dy] * inv;
            re += v * COS9[tt]; im += v * SIN9[tt];
        }
        Af[f*4096 + pr] = make_float2(re, im);
    }
}

// ---------------- M = 1.1 I + g A^H A ; W^T = (0.9 I - g A^H A)^T ----------
__global__ __launch_bounds__(256) void k_mw(const float2* __restrict__ Af,
                                            const float* __restrict__ gp,
                                            float2* __restrict__ Mmat,
                                            float2* __restrict__ WmT) {
    int l = blockIdx.x; int f = CANON(l);
    float g = gp[0];
    __shared__ float2 Al[4096];
    for (int i = threadIdx.x; i < 4096; i += 256) Al[i] = Af[f*4096 + i];
    __syncthreads();
    for (int e = threadIdx.x; e < 4096; e += 256) {
        int i = e >> 6, j = e & 63;
        float sr = 0.f, si = 0.f;
        for (int o = 0; o < 64; o++) {
            float2 a = Al[o*64 + i], b = Al[o*64 + j];
            sr += a.x*b.x + a.y*b.y;
            si += a.x*b.y - a.y*b.x;
        }
        Mmat[f*4096 + e] = make_float2((i==j ? 1.1f : 0.f) + g*sr, g*si);
        WmT [f*4096 + j*64 + i] = make_float2((i==j ? 0.9f : 0.f) - g*sr, -g*si);
    }
}

// ---------------- in-place Gauss-Jordan inverse, conflict-free -------------
// LDS rows padded to 65 float2. Writes back transposed: Mio[f][c][o].
__global__ __launch_bounds__(256) void k_inv(float2* __restrict__ Mio) {
    int l = blockIdx.x; int f = CANON(l);
    __shared__ float2 M[64*65];
    __shared__ float2 rowk[64];
    __shared__ float2 fcol[64];
    int tid = threadIdx.x;
    float2* Mg = Mio + f*4096;
    for (int e = tid; e < 4096; e += 256) M[(e>>6)*65 + (e&63)] = Mg[e];
    __syncthreads();
    int j = tid & 63, ig = tid >> 6;
    for (int k = 0; k < 64; k++) {
        if (ig == 0) {
            float2 d = M[k*65 + k];
            float den = 1.f / (d.x*d.x + d.y*d.y);
            float pr = d.x*den, pi = -d.y*den;
            float2 m = M[k*65 + j];
            rowk[j] = (j == k) ? make_float2(pr, pi)
                               : make_float2(m.x*pr - m.y*pi, m.x*pi + m.y*pr);
        } else if (ig == 1) {
            fcol[j] = M[j*65 + k];
        }
        __syncthreads();
        #pragma unroll 4
        for (int s = 0; s < 16; s++) {
            int i = (ig << 4) + s;
            if (i == k) {
                M[i*65 + j] = rowk[j];
            } else {
                float2 fi = fcol[i];
                if (j == k) {
                    float2 rk = rowk[k];
                    M[i*65 + j] = make_float2(-(fi.x*rk.x - fi.y*rk.y),
                                              -(fi.x*rk.y + fi.y*rk.x));
                } else {
                    float2 r = rowk[j]; float2 m = M[i*65 + j];
                    M[i*65 + j] = make_float2(m.x - (fi.x*r.x - fi.y*r.y),
                                              m.y - (fi.x*r.y + fi.y*r.x));
                }
            }
        }
        __syncthreads();
    }
    for (int e = tid; e < 4096; e += 256) {
        int i2 = e >> 6, j2 = e & 63;
        Mio[f*4096 + j2*64 + i2] = M[i2*65 + j2];
    }
}

// ---------------- standalone forward FFT of a real field -> canonical Tf ---
__global__ __launch_bounds__(256) void k_fft(const float* __restrict__ in,
                                             float2* __restrict__ Tf) {
    __shared__ float  tre[16][81];
    __shared__ float2 S[16][81];
    int tid = threadIdx.x;
    int img0 = blockIdx.x * 16;
    int tl = tid & 15, th = tid >> 4;
    int gb = (img0 + th)*81;
    #pragma unroll
    for (int k = 0; k < 6; k++) {
        int p = tl + 16*k;
        if (p < 81) tre[th][p] = in[gb + p];
    }
    __syncthreads();
    #pragma unroll
    for (int k = 0; k < 6; k++) {
        int idx = tl + 16*k;
        if (idx < 81) {
            int r = idx/9, ky = idx%9;
            float sr = 0.f, si = 0.f;
            int tt = 0;
            #pragma unroll
            for (int xx = 0; xx < 9; xx++) {
                float v = tre[th][r*9 + xx];
                sr += v*COS9[tt]; si -= v*SIN9[tt];
                tt += ky; if (tt >= 9) tt -= 9;
            }
            S[th][idx] = make_float2(sr, si);
        }
    }
    __syncthreads();
    #pragma unroll
    for (int k = 0; k < 3; k++) {
        int l = th + 16*k;
        if (l < NCAN) {
            int f = CANON(l);
            int kx = f/9, ky = f%9;
            float fr = 0.f, fim = 0.f;
            int tt = 0;
            #pragma unroll
            for (int r = 0; r < 9; r++) {
                float2 s = S[tl][r*9 + ky];
                float c = COS9[tt], sn = SIN9[tt];
                fr  += s.x*c + s.y*sn;
                fim += s.y*c - s.x*sn;
                tt += kx; if (tt >= 9) tt -= 9;
            }
            Tf[f*NIMG + img0 + tl] = make_float2(fr, fim);
        }
    }
}

// ---------------- per-frequency matvec (canonical only) + err check --------
__global__ __launch_bounds__(256) void k_mv(const float2* __restrict__ Tf,
                                            float2* __restrict__ Yf,
                                            const float2* __restrict__ V,
                                            const float2* __restrict__ errp,
                                            int* __restrict__ flag,
                                            int iter, int inloop) {
    __shared__ float2 Vl[4096];
    __shared__ float2 Tl[32*65];
    __shared__ float2 red2[256];
    int tid = threadIdx.x;
    if (inloop) {
        if (*flag) return;
        if (iter > 0) {
            float d2 = 0.f, n2 = 0.f;
            const float2* ep = errp + (iter-1)*1024;
            for (int q = tid; q < 1024; q += 256) { float2 e = ep[q]; d2 += e.x; n2 += e.y; }
            red2[tid] = make_float2(d2, n2);
            __syncthreads();
            for (int w = 128; w > 0; w >>= 1) {
                if (tid < w) { red2[tid].x += red2[tid+w].x; red2[tid].y += red2[tid+w].y; }
                __syncthreads();
            }
            float2 t = red2[0];
            if (sqrtf(t.x) <= TOLF * (1e-6f + sqrtf(t.y))) {
                if (tid == 0) *flag = 1;
                return;
            }
        }
    }
    int l = blockIdx.x >> 3, bc = blockIdx.x & 7;
    int f = CANON(l);
    const float2* Vg = V + f*4096;
    for (int e = tid; e < 4096; e += 256) Vl[e] = Vg[e];
    const float2* Tg = Tf + f*NIMG + bc*2048;
    for (int e = tid; e < 2048; e += 256) Tl[(e>>6)*65 + (e&63)] = Tg[e];
    __syncthreads();
    int r = tid >> 3, to = tid & 7;
    float2 acc[8];
    #pragma unroll
    for (int k = 0; k < 8; k++) acc[k] = make_float2(0.f, 0.f);
    const float2* trow = Tl + r*65;
    for (int c = 0; c < 64; c++) {
        float2 t = trow[c];
        #pragma unroll
        for (int k = 0; k < 8; k++) {
            float2 v = Vl[c*64 + to + 8*k];
            acc[k].x += v.x*t.x - v.y*t.y;
            acc[k].y += v.x*t.y + v.y*t.x;
        }
    }
    float2* Yg = Yf + f*NIMG + bc*2048 + r*64;
    #pragma unroll
    for (int k = 0; k < 8; k++) Yg[to + 8*k] = acc[k];
}

// ---------------- fused: finv(iter) + ffwd(iter+1) -------------------------
__global__ __launch_bounds__(256) void k_fuse(const float2* __restrict__ Yf,
                                              float* __restrict__ u12g,
                                              float* __restrict__ zg,
                                              const float* __restrict__ bias,
                                              float2* __restrict__ Tf,
                                              float2* __restrict__ errp,
                                              const int* __restrict__ flag,
                                              int iter) {
    if (*flag) return;
    __shared__ float2 Yc[16][81];
    __shared__ float2 T1[16][81];
    __shared__ float  zl[16][81];
    __shared__ float  ul[16][81];
    __shared__ float2 red2[256];
    int tid = threadIdx.x;
    int img0 = blockIdx.x * 16;
    int tl = tid & 15, th = tid >> 4;
    // load canonical freqs; reconstruct mirrors by conjugation (z real)
    #pragma unroll
    for (int k = 0; k < 3; k++) {
        int l = th + 16*k;
        if (l < NCAN) {
            int f = CANON(l);
            float2 a = Yf[f*NIMG + img0 + tl];
            Yc[tl][f] = a;
            int xx = f/9, yy = f%9;
            int fm = ((9-xx)%9)*9 + (9-yy)%9;
            if (fm != f) Yc[tl][fm] = make_float2(a.x, -a.y);
        }
    }
    __syncthreads();
    // IFFT stage 1
    #pragma unroll
    for (int k = 0; k < 6; k++) {
        int idx = tl + 16*k;
        if (idx < 81) {
            int r = idx/9, ky = idx%9;
            float sr = 0.f, si = 0.f;
            int tt = 0;
            #pragma unroll
            for (int kx = 0; kx < 9; kx++) {
                float2 a = Yc[th][kx*9 + ky];
                float c = COS9[tt], sn = SIN9[tt];
                sr += a.x*c - a.y*sn;
                si += a.x*sn + a.y*c;
                tt += r; if (tt >= 9) tt -= 9;
            }
            T1[th][idx] = make_float2(sr, si);
        }
    }
    __syncthreads();
    // IFFT stage 2 + PR update; keep zn/un in LDS
    float d2a = 0.f, n2a = 0.f;
    int gb = (img0 + th)*81;
    #pragma unroll
    for (int k = 0; k < 6; k++) {
        int p = tl + 16*k;
        if (p < 81) {
            int r = p/9, xc = p%9;
            float yr = 0.f;
            int tt = 0;
            #pragma unroll
            for (int ky = 0; ky < 9; ky++) {
                float2 a = T1[th][r*9 + ky];
                yr += a.x*COS9[tt] - a.y*SIN9[tt];
                tt += xc; if (tt >= 9) tt -= 9;
            }
            yr *= (1.f/81.f);
            bool interior = (r >= 1 && r <= 7 && xc >= 1 && xc <= 7);
            float un = 2.f*yr - u12g[gb+p];
            float zn = interior ? fmaxf(un, 0.f) : 0.f;
            float zo = zg[gb+p];
            float d = zn - zo;
            d2a += d*d; n2a += zn*zn;
            zl[th][p] = zn; ul[th][p] = un;
            zg[gb+p] = zn;
        }
    }
    red2[tid] = make_float2(d2a, n2a);
    __syncthreads();
    for (int w = 128; w > 0; w >>= 1) {
        if (tid < w) { red2[tid].x += red2[tid+w].x; red2[tid].y += red2[tid+w].y; }
        __syncthreads();
    }
    if (tid == 0) errp[iter*1024 + blockIdx.x] = red2[0];
    // ---- phase B: ffwd(iter+1) : u12 = 2z-u ; FFT2(u12+bias) ----
    float* tre = (float*)Yc;           // alias (Yc dead)
    #pragma unroll
    for (int k = 0; k < 6; k++) {
        int p = tl + 16*k;
        if (p < 81) {
            float v = 2.f*zl[th][p] - ul[th][p];
            u12g[gb+p] = v;
            tre[th*81 + p] = v + bias[gb+p];
        }
    }
    __syncthreads();
    float2* S = (float2*)T1;           // alias (T1 dead)
    #pragma unroll
    for (int k = 0; k < 6; k++) {
        int idx = tl + 16*k;
        if (idx < 81) {
            int r = idx/9, ky = idx%9;
            float sr = 0.f, si = 0.f;
            int tt = 0;
            #pragma unroll
            for (int xx = 0; xx < 9; xx++) {
                float v = tre[th*81 + r*9 + xx];
                sr += v*COS9[tt]; si -= v*SIN9[tt];
                tt += ky; if (tt >= 9) tt -= 9;
            }
            S[th*81 + idx] = make_float2(sr, si);
        }
    }
    __syncthreads();
    #pragma unroll
    for (int k = 0; k < 3; k++) {
        int l = th + 16*k;
        if (l < NCAN) {
            int f = CANON(l);
            int kx = f/9, ky = f%9;
            float fr = 0.f, fim = 0.f;
            int tt = 0;
            #pragma unroll
            for (int r = 0; r < 9; r++) {
                float2 s = S[tl*81 + r*9 + ky];
                float c = COS9[tt], sn = SIN9[tt];
                fr  += s.x*c + s.y*sn;
                fim += s.y*c - s.x*sn;
                tt += kx; if (tt >= 9) tt -= 9;
            }
            Tf[f*NIMG + img0 + tl] = make_float2(fr, fim);
        }
    }
}

// ---------------- final: IFFT(W z) -> relu(+bias) masked -> crop write -----
__global__ __launch_bounds__(256) void k_crop(const float2* __restrict__ Yf,
                                              const float* __restrict__ bias,
                                              float* __restrict__ zc) {
    __shared__ float2 Yc[16][81];
    __shared__ float2 T1[16][81];
    int tid = threadIdx.x;
    int img0 = blockIdx.x * 16;
    int tl = tid & 15, th = tid >> 4;
    #pragma unroll
    for (int k = 0; k < 3; k++) {
        int l = th + 16*k;
        if (l < NCAN) {
            int f = CANON(l);
            float2 a = Yf[f*NIMG + img0 + tl];
            Yc[tl][f] = a;
            int xx = f/9, yy = f%9;
            int fm = ((9-xx)%9)*9 + (9-yy)%9;
            if (fm != f) Yc[tl][fm] = make_float2(a.x, -a.y);
        }
    }
    __syncthreads();
    #pragma unroll
    for (int k = 0; k < 6; k++) {
        int idx = tl + 16*k;
        if (idx < 81) {
            int r = idx/9, ky = idx%9;
            float sr = 0.f, si = 0.f;
            int tt = 0;
            #pragma unroll
            for (int kx = 0; kx < 9; kx++) {
                float2 a = Yc[th][kx*9 + ky];
                float c = COS9[tt], sn = SIN9[tt];
                sr += a.x*c - a.y*sn;
                si += a.x*sn + a.y*c;
                tt += r; if (tt >= 9) tt -= 9;
            }
            T1[th][idx] = make_float2(sr, si);
        }
    }
    __syncthreads();
    int gb = (img0 + th)*81;
    #pragma unroll
    for (int k = 0; k < 6; k++) {
        int p = tl + 16*k;
        if (p < 81) {
            int r = p/9, xc = p%9;
            if (r >= 1 && r <= 7 && xc >= 1 && xc <= 7) {
                float yr = 0.f;
                int tt = 0;
                #pragma unroll
                for (int ky = 0; ky < 9; ky++) {
                    float2 a = T1[th][r*9 + ky];
                    yr += a.x*COS9[tt] - a.y*SIN9[tt];
                    tt += xc; if (tt >= 9) tt -= 9;
                }
                yr *= (1.f/81.f);
                float zn = fmaxf(yr + bias[gb+p], 0.f);
                int img = img0 + th;
                zc[(img >> 6)*3136 + (img & 63)*49 + (r-1)*7 + (xc-1)] = zn;
            }
        }
    }
}

// ---------------- fc1: (256x3136)x(512x3136)^T + b, relu -------------------
__global__ __launch_bounds__(256) void k_fc1(const float* __restrict__ A,
                                             const float* __restrict__ W,
                                             const float* __restrict__ bb,
                                             float* __restrict__ H) {
    int bt = blockIdx.x >> 5, ot = blockIdx.x & 31;
    int b0 = bt*16, o0 = ot*16;
    __shared__ float At[16][65], Bt[16][65];
    int tid = threadIdx.x;
    int row = tid >> 6, col = tid & 63;
    int tb = tid >> 4, to = tid & 15;
    float acc = 0.f;
    for (int k0 = 0; k0 < 3136; k0 += 64) {
        #pragma unroll
        for (int s = 0; s < 4; s++) {
            int rr = row + s*4;
            At[rr][col] = A[(b0+rr)*3136 + k0 + col];
            Bt[rr][col] = W[(o0+rr)*3136 + k0 + col];
        }
        __syncthreads();
        #pragma unroll
        for (int kk = 0; kk < 64; kk++)
            acc += At[tb][kk] * Bt[to][kk];
        __syncthreads();
    }
    H[(b0+tb)*512 + o0+to] = fmaxf(acc + bb[o0+to], 0.f);
}

// ---------------- fc2: (256x512)x(18x512)^T + b ----------------------------
__global__ __launch_bounds__(256) void k_fc2(const float* __restrict__ H,
                                             const float* __restrict__ W,
                                             const float* __restrict__ bb,
                                             float* __restrict__ out) {
    int idx = blockIdx.x*256 + threadIdx.x;
    if (idx >= 4608) return;
    int b = idx/18, o = idx%18;
    const float* h = H + b*512;
    const float* w = W + o*512;
    float acc = 0.f;
    for (int k = 0; k < 512; k++) acc += h[k]*w[k];
    out[idx] = acc + bb[o];
}

// ---------------------------------------------------------------------------
extern "C" void kernel_launch(void* const* d_in, const int* in_sizes, int n_in,
                              void* d_out, int out_size, void* d_ws, size_t ws_size,
                              hipStream_t stream) {
    (void)in_sizes; (void)n_in; (void)out_size; (void)ws_size;
    const float* x   = (const float*)d_in[0];
    const float* c1w = (const float*)d_in[1];
    const float* c1b = (const float*)d_in[2];
    const float* c2w = (const float*)d_in[3];
    const float* c2b = (const float*)d_in[4];
    const float* Uw  = (const float*)d_in[5];
    const float* Ub  = (const float*)d_in[6];
    const float* Aw  = (const float*)d_in[7];
    const float* gp  = (const float*)d_in[8];
    const float* f1w = (const float*)d_in[9];
    const float* f1b = (const float*)d_in[10];
    const float* f2w = (const float*)d_in[11];
    const float* f2b = (const float*)d_in[12];

    float* ws = (float*)d_ws;
    float*  h1   = ws + 0;                       // 3,276,800 f
    float2* Tf   = (float2*)(ws + 0);            // alias h1 (dead after conv2)
    float*  h2   = ws + 3276800;                 // 1,327,104 f
    float*  bias = ws + 4603904;                 // 1,327,104 f
    float*  z    = ws + 5931008;                 // 1,327,104 f
    float*  u12  = ws + 7258112;                 // 1,327,104 f
    float2* Yf   = (float2*)(ws + 8585216);      // 1,327,104 c2
    float2* Af   = (float2*)(ws + 11239424);     // 331,776 c2 (sparse canonical)
    float2* Minv = (float2*)(ws + 11902976);     // 331,776 c2
    float2* WmT  = (float2*)(ws + 12566528);     // 331,776 c2
    float*  zc   = ws + 13230080;                // 802,816 f
    float*  hfc  = ws + 14032896;                // 131,072 f
    float2* errp = (float2*)(ws + 14163968);     // 50*1024 c2 (d2,n2)
    float*  sc   = ws + 14266368;                // nrm, invnrm
    int*    flag = (int*)(ws + 14266370);

    hipMemsetAsync(z, 0, (size_t)2*1327104*sizeof(float), stream);   // z, u12
    hipMemsetAsync(flag, 0, sizeof(int), stream);

    k_norm <<<1,   256, 0, stream>>>(Aw, sc);
    k_conv1<<<1024,256, 0, stream>>>(x, c1w, c1b, h1);
    k_conv2<<<256, 256, 0, stream>>>(h1, c2w, c2b, h2);
    k_bias <<<256, 256, 0, stream>>>(h2, Uw, Ub, bias);
    k_af   <<<NCAN,256, 0, stream>>>(Aw, sc, Af);
    k_mw   <<<NCAN,256, 0, stream>>>(Af, gp, Minv, WmT);
    k_inv  <<<NCAN,256, 0, stream>>>(Minv);

    // iteration 0 forward: u12 = 0, so T = FFT(bias)
    k_fft<<<1024,256,0,stream>>>(bias, Tf);
    for (int it = 0; it < MAXIT; it++) {
        k_mv  <<<NCAN*8,256,0,stream>>>(Tf, Yf, Minv, errp, flag, it, 1);
        k_fuse<<<1024,  256,0,stream>>>(Yf, u12, z, bias, Tf, errp, flag, it);
    }
    // final pass: brelu(W z + bias) -> crop
    k_fft <<<1024,  256,0,stream>>>(z, Tf);
    k_mv  <<<NCAN*8,256,0,stream>>>(Tf, Yf, WmT, errp, flag, 0, 0);
    k_crop<<<1024,  256,0,stream>>>(Yf, bias, zc);

    k_fc1<<<512,256,0,stream>>>(zc, f1w, f1b, hfc);
    k_fc2<<<18, 256,0,stream>>>(hfc, f2w, f2b, (float*)d_out);
}